// Round 4
// baseline (29.249 us; speedup 1.0000x reference)
//
#include <hip/hip_runtime.h>
#include <math.h>

#define NB 32
#define NJ 64
#define NC 7
#define NH 128
#define NW 128
#define HW (NH*NW)          // 16384 floats per (b,j)
#define SPLIT 4             // quarter-scans per (b,j)
#define PART4 (HW/4/SPLIT)  // 1024 float4 per part
#define SMOOTHING 0.1f

// Kernel 1: one block per (b,j,part). Scans 4096 floats (1024 float4, 4/thread),
// writes (maxval, arg flat index) partial to ws. 8192 blocks = 4 generations of
// waves -> early finishers backfill, hiding completion skew.
__global__ __launch_bounds__(256) void labelloss_scan_kernel(
    const float* __restrict__ heatmap,
    float* __restrict__ wsv,
    int*   __restrict__ wsi)
{
    const int blk  = blockIdx.x;        // (b*NJ + j)*SPLIT + part
    const int bj   = blk >> 2;
    const int part = blk & 3;
    const float4* __restrict__ hm4 =
        (const float4*)heatmap + (size_t)bj * (HW/4) + (size_t)part * PART4;

    const int t = threadIdx.x;
    float best    = -INFINITY;
    int   bestIdx = HW;                 // sentinel

    // Per-thread visit order is increasing -> strict '>' keeps first-occurrence.
    #pragma unroll
    for (int i = 0; i < PART4/256; ++i) {
        const int i4 = t + (i << 8);
        const float4 v = hm4[i4];
        const int base = (part * PART4 + i4) << 2;   // flat index within (b,j)
        if (v.x > best) { best = v.x; bestIdx = base;     }
        if (v.y > best) { best = v.y; bestIdx = base + 1; }
        if (v.z > best) { best = v.z; bestIdx = base + 2; }
        if (v.w > best) { best = v.w; bestIdx = base + 3; }
    }

    // wave-64 reduce (max, tie -> min index)
    #pragma unroll
    for (int off = 32; off > 0; off >>= 1) {
        const float ov = __shfl_down(best, off);
        const int   oi = __shfl_down(bestIdx, off);
        if (ov > best || (ov == best && oi < bestIdx)) { best = ov; bestIdx = oi; }
    }

    __shared__ float sv[4];
    __shared__ int   si[4];
    const int wid  = t >> 6;
    const int lane = t & 63;
    if (lane == 0) { sv[wid] = best; si[wid] = bestIdx; }
    __syncthreads();

    if (t == 0) {
        #pragma unroll
        for (int w = 1; w < 4; ++w) {
            if (sv[w] > best || (sv[w] == best && si[w] < bestIdx)) { best = sv[w]; bestIdx = si[w]; }
        }
        wsv[blk] = best;
        wsi[blk] = bestIdx;
    }
}

// Kernel 2: one wave per b. Thread j merges its SPLIT partials (one float4 +
// one int4 load), does the 7-class smoothed BCE at the argmax location, then
// wave-reduces the mean. Fully overwrites d_out.
__global__ __launch_bounds__(64) void labelloss_finish_kernel(
    const float* __restrict__ pred,
    const float* __restrict__ gt,
    const float* __restrict__ wsv,
    const int*   __restrict__ wsi,
    float* __restrict__ out)
{
    const int b = blockIdx.x;
    const int j = threadIdx.x;
    const int p0 = (b * NJ + j) * SPLIT;

    const float4 pv = *(const float4*)(wsv + p0);
    const int4   pi = *(const int4*)(wsi + p0);

    // Parts are in increasing-index order, so strict '>' in order keeps the
    // first-occurrence argmax.
    float best    = pv.x;
    int   bestIdx = pi.x;
    if (pv.y > best) { best = pv.y; bestIdx = pi.y; }
    if (pv.z > best) { best = pv.z; bestIdx = pi.z; }
    if (pv.w > best) { best = pv.w; bestIdx = pi.w; }

    const int x = bestIdx >> 7;         // flat // 128
    const int y = bestIdx & 127;        // flat % 128

    float s = 0.0f;
    #pragma unroll
    for (int c = 0; c < NC; ++c) {
        const float z  = pred[(((size_t)b * NC + c) * NH + x) * NW + y];
        const float td = (1.0f - SMOOTHING) * gt[((size_t)b * NJ + j) * NC + c]
                         + SMOOTHING / (float)NC;
        s += fmaxf(z, 0.0f) - z * td + log1pf(expf(-fabsf(z)));
    }

    #pragma unroll
    for (int off = 32; off > 0; off >>= 1) s += __shfl_down(s, off);
    if (j == 0) out[b] = s * (1.0f / (float)NJ);
}

extern "C" void kernel_launch(void* const* d_in, const int* in_sizes, int n_in,
                              void* d_out, int out_size, void* d_ws, size_t ws_size,
                              hipStream_t stream) {
    const float* pred    = (const float*)d_in[0];
    const float* gt      = (const float*)d_in[1];
    const float* heatmap = (const float*)d_in[2];
    float* out = (float*)d_out;
    float* wsv = (float*)d_ws;                          // 8192 floats
    int*   wsi = (int*)((char*)d_ws + NB*NJ*SPLIT*4);   // 8192 ints

    labelloss_scan_kernel<<<NB * NJ * SPLIT, 256, 0, stream>>>(heatmap, wsv, wsi);
    labelloss_finish_kernel<<<NB, 64, 0, stream>>>(pred, gt, wsv, wsi, out);
}

// Round 5
// 27.253 us; speedup vs baseline: 1.0732x; 1.0732x over previous
//
#include <hip/hip_runtime.h>
#include <math.h>

#define NB 32
#define NJ 64
#define NC 7
#define NH 128
#define NW 128
#define HW (NH*NW)          // 16384 floats per (b,j)
#define SPLIT 2             // half-scans per (b,j)
#define PART4 (HW/4/SPLIT)  // 2048 float4 per half
#define SMOOTHING 0.1f

typedef float f32x4 __attribute__((ext_vector_type(4)));

// Kernel 1: one block per (b,j,half). Scans 8192 floats (2048 float4, 8/thread)
// with non-temporal loads (single-touch stream, skip cache allocation), writes
// (maxval, arg flat index) partial to ws. 4096 blocks = 2 generations of waves.
__global__ __launch_bounds__(256) void labelloss_scan_kernel(
    const float* __restrict__ heatmap,
    float* __restrict__ wsv,
    int*   __restrict__ wsi)
{
    const int blk  = blockIdx.x;        // (b*NJ + j)*SPLIT + half
    const int bj   = blk >> 1;
    const int half = blk & 1;
    const f32x4* __restrict__ hm4 =
        (const f32x4*)heatmap + (size_t)bj * (HW/4) + (size_t)half * PART4;

    const int t = threadIdx.x;
    float best    = -INFINITY;
    int   bestIdx = HW;                 // sentinel

    // Per-thread visit order is increasing -> strict '>' keeps first-occurrence.
    #pragma unroll
    for (int i = 0; i < PART4/256; ++i) {
        const int i4 = t + (i << 8);
        const f32x4 v = __builtin_nontemporal_load(&hm4[i4]);
        const int base = (half * PART4 + i4) << 2;   // flat index within (b,j)
        if (v[0] > best) { best = v[0]; bestIdx = base;     }
        if (v[1] > best) { best = v[1]; bestIdx = base + 1; }
        if (v[2] > best) { best = v[2]; bestIdx = base + 2; }
        if (v[3] > best) { best = v[3]; bestIdx = base + 3; }
    }

    // wave-64 reduce (max, tie -> min index)
    #pragma unroll
    for (int off = 32; off > 0; off >>= 1) {
        const float ov = __shfl_down(best, off);
        const int   oi = __shfl_down(bestIdx, off);
        if (ov > best || (ov == best && oi < bestIdx)) { best = ov; bestIdx = oi; }
    }

    __shared__ float sv[4];
    __shared__ int   si[4];
    const int wid  = t >> 6;
    const int lane = t & 63;
    if (lane == 0) { sv[wid] = best; si[wid] = bestIdx; }
    __syncthreads();

    if (t == 0) {
        #pragma unroll
        for (int w = 1; w < 4; ++w) {
            if (sv[w] > best || (sv[w] == best && si[w] < bestIdx)) { best = sv[w]; bestIdx = si[w]; }
        }
        wsv[blk] = best;
        wsi[blk] = bestIdx;
    }
}

// Kernel 2: one wave per b. Thread j: issue independent gt loads first, merge
// its 2 partials (vectorized), gather pred at argmax, BCE, wave-reduce mean.
__global__ __launch_bounds__(64) void labelloss_finish_kernel(
    const float* __restrict__ pred,
    const float* __restrict__ gt,
    const float* __restrict__ wsv,
    const int*   __restrict__ wsi,
    float* __restrict__ out)
{
    const int b = blockIdx.x;
    const int j = threadIdx.x;
    const int p0 = (b * NJ + j) * SPLIT;

    // Independent loads first: gt row (7 floats) + partials; only the pred
    // gather is on the dependent (argmax) path.
    float td[NC];
    #pragma unroll
    for (int c = 0; c < NC; ++c)
        td[c] = (1.0f - SMOOTHING) * gt[((size_t)b * NJ + j) * NC + c]
                + SMOOTHING / (float)NC;

    const float2 pv = *(const float2*)(wsv + p0);
    const int2   pi = *(const int2*)(wsi + p0);

    // Halves are in increasing-index order: strict '>' keeps first-occurrence.
    float best    = pv.x;
    int   bestIdx = pi.x;
    if (pv.y > best) { best = pv.y; bestIdx = pi.y; }

    const int x = bestIdx >> 7;         // flat // 128
    const int y = bestIdx & 127;        // flat % 128

    float s = 0.0f;
    #pragma unroll
    for (int c = 0; c < NC; ++c) {
        const float z = pred[(((size_t)b * NC + c) * NH + x) * NW + y];
        s += fmaxf(z, 0.0f) - z * td[c] + log1pf(expf(-fabsf(z)));
    }

    #pragma unroll
    for (int off = 32; off > 0; off >>= 1) s += __shfl_down(s, off);
    if (j == 0) out[b] = s * (1.0f / (float)NJ);
}

extern "C" void kernel_launch(void* const* d_in, const int* in_sizes, int n_in,
                              void* d_out, int out_size, void* d_ws, size_t ws_size,
                              hipStream_t stream) {
    const float* pred    = (const float*)d_in[0];
    const float* gt      = (const float*)d_in[1];
    const float* heatmap = (const float*)d_in[2];
    float* out = (float*)d_out;
    float* wsv = (float*)d_ws;                          // 4096 floats
    int*   wsi = (int*)((char*)d_ws + NB*NJ*SPLIT*4);   // 4096 ints

    labelloss_scan_kernel<<<NB * NJ * SPLIT, 256, 0, stream>>>(heatmap, wsv, wsi);
    labelloss_finish_kernel<<<NB, 64, 0, stream>>>(pred, gt, wsv, wsi, out);
}